// Round 6
// baseline (1212.098 us; speedup 1.0000x reference)
//
#include <hip/hip_runtime.h>
#include <math.h>

#define DEV __device__ __forceinline__

typedef _Float16 f16x8 __attribute__((ext_vector_type(8)));
typedef _Float16 f16x4 __attribute__((ext_vector_type(4)));
typedef float    f32x4 __attribute__((ext_vector_type(4)));

DEV float sigmoidf_(float x){ return 1.0f/(1.0f + expf(-x)); }

DEV float wred64(float x){
    #pragma unroll
    for (int off=32; off; off>>=1) x += __shfl_xor(x, off);
    return x;
}

#define MFMA16(a,b,c) __builtin_amdgcn_mfma_f32_16x16x32_f16(a,b,c,0,0,0)

// ---------------- prep: faW, fvW, bpack(av_vw), bpack2(v2w) ------------
__global__ __launch_bounds__(256) void k_prep(
    const float* __restrict__ fa_w1, const float* __restrict__ fa_w2, float* __restrict__ faW,
    const float* __restrict__ fv_w1, const float* __restrict__ fv_w2, float* __restrict__ fvW,
    const float* __restrict__ av_vw, _Float16* __restrict__ Bh, _Float16* __restrict__ Bl,
    const float* __restrict__ v2w, _Float16* __restrict__ Wh, _Float16* __restrict__ Wl)
{
    int bid = blockIdx.x, t = threadIdx.x;
    if (bid < 64){
        int idx = bid*256+t; int m = idx>>7, n = idx&127;
        float acc=0.f;
        for (int k=0;k<256;k++) acc += fa_w1[m*256+k]*fa_w2[k*128+n];
        faW[idx]=acc;
    } else if (bid < 320){
        int idx = (bid-64)*256+t; int m = idx>>7, n = idx&127;
        float acc=0.f;
        for (int k=0;k<256;k++) acc += fv_w1[m*256+k]*fv_w2[k*128+n];
        fvW[idx]=acc;
    } else if (bid < 1344){
        int o = (bid-320)*256+t;
        int j = o & 7, l16 = (o>>3)&15, kg = (o>>7)&3, nf = (o>>9)&31, kt = o>>14;
        int k = kt*32 + kg*8 + j, n = nf*16 + l16;
        float x = av_vw[(size_t)k*512 + n];
        _Float16 h = (_Float16)x;
        Bh[o] = h; Bl[o] = (_Float16)(x - (float)h);
    } else {
        int o = (bid-1344)*256+t;
        int j = o & 7, l16 = (o>>3)&15, kg = (o>>7)&3, qf = (o>>9)&3, kbg = o>>11;
        int k = kbg*32 + kg*8 + j, q = qf*16 + l16;
        float x = (q < 49) ? v2w[(size_t)k*49 + q] : 0.f;
        _Float16 h = (_Float16)x;
        Wh[o] = h; Wl[o] = (_Float16)(x - (float)h);
    }
}

// ---------------- prep2: pack tail GEMM weights into frag layout -------
DEV void packone(const float* __restrict__ src, int N, int NfrTot, int nfOff,
                 _Float16* __restrict__ Dh, _Float16* __restrict__ Dl, int o){
    int j = o&7, l16 = (o>>3)&15, kg = (o>>7)&3;
    int rest = o>>9;
    int nfl = rest % (N>>4), kt = rest / (N>>4);
    int k = kt*32 + kg*8 + j, n = nfl*16 + l16;
    float x = src[(size_t)k*N + n];
    _Float16 h = (_Float16)x;
    size_t d = ((size_t)kt*NfrTot + nfOff + nfl)*512 + kg*128 + l16*8 + j;
    Dh[d] = h; Dl[d] = (_Float16)(x - (float)h);
}

__global__ __launch_bounds__(256) void k_prep2(
    const float* __restrict__ fvW,
    const float* __restrict__ la_wih, const float* __restrict__ lv_wih,
    const float* __restrict__ vL1, const float* __restrict__ vL2,
    const float* __restrict__ aL1, const float* __restrict__ aL2,
    const float* __restrict__ vfc, const float* __restrict__ afc,
    _Float16* PKfv_h, _Float16* PKfv_l,
    _Float16* PKxa_h, _Float16* PKxa_l,
    _Float16* PKxv_h, _Float16* PKxv_l,
    _Float16* PKvl_h, _Float16* PKvl_l,
    _Float16* PKal_h, _Float16* PKal_l,
    _Float16* PKvf_h, _Float16* PKvf_l,
    _Float16* PKaf_h, _Float16* PKaf_l)
{
    int seg = blockIdx.x >> 8;
    int o = (blockIdx.x & 255)*256 + threadIdx.x;   // [0,65536)
    switch(seg){
    case 0:  packone(fvW,            128,  8,  0, PKfv_h, PKfv_l, o); break;
    case 1:  packone(la_wih,         512, 64,  0, PKxa_h, PKxa_l, o); break;
    case 2:  packone(la_wih+65536,   512, 64, 32, PKxa_h, PKxa_l, o); break;
    case 3:  packone(lv_wih,         512, 64,  0, PKxv_h, PKxv_l, o); break;
    case 4:  packone(lv_wih+65536,   512, 64, 32, PKxv_h, PKxv_l, o); break;
    case 5:  packone(vL1,            256, 32,  0, PKvl_h, PKvl_l, o); break;
    case 6:  packone(vL2,            256, 32, 16, PKvl_h, PKvl_l, o); break;
    case 7:  packone(aL1,            256, 32,  0, PKal_h, PKal_l, o); break;
    case 8:  packone(aL2,            256, 32, 16, PKal_h, PKal_l, o); break;
    case 9:  packone(vfc,            256, 16,  0, PKvf_h, PKvf_l, o); break;
    default: packone(afc,            256, 16,  0, PKaf_h, PKaf_l, o); break;
    }
}

// ---------------- fused fa + a_h + ga, 4 bt per block ------------------
__global__ __launch_bounds__(256) void k_faga(
    const float* __restrict__ audio, const float* __restrict__ faW,
    const float* __restrict__ av_aw, const float* __restrict__ av_ab,
    const float* __restrict__ av_gw, float* __restrict__ fa, float* __restrict__ gGA)
{
    int b0 = blockIdx.x*4; int t = threadIdx.x;
    __shared__ float sau[4][128], sfa[4][128], sah[4][512];
    for (int i=t;i<512;i+=256){ int bt=i>>7,k=i&127; sau[bt][k]=audio[(size_t)(b0+bt)*128+k]; }
    __syncthreads();
    for (int u=0;u<2;u++){
        int i=t+u*256, bt=i>>7, n=i&127;
        float acc=0.f;
        for (int k4=0;k4<32;k4++){
            float4 x4=*(const float4*)&sau[bt][k4*4];
            acc+=x4.x*faW[(k4*4)*128+n]+x4.y*faW[(k4*4+1)*128+n]
                +x4.z*faW[(k4*4+2)*128+n]+x4.w*faW[(k4*4+3)*128+n];
        }
        sfa[bt][n]=acc; fa[(size_t)(b0+bt)*128+n]=acc;
    }
    __syncthreads();
    for (int u=0;u<2;u++){
        int n=t+u*256;
        float bv=av_ab[n];
        float acc[4]={bv,bv,bv,bv};
        for (int k4=0;k4<32;k4++){
            float w0=av_aw[(k4*4)*512+n], w1=av_aw[(k4*4+1)*512+n],
                  w2=av_aw[(k4*4+2)*512+n], w3=av_aw[(k4*4+3)*512+n];
            #pragma unroll
            for (int bt=0;bt<4;bt++){
                float4 x4=*(const float4*)&sfa[bt][k4*4];
                acc[bt]+=x4.x*w0+x4.y*w1+x4.z*w2+x4.w*w3;
            }
        }
        #pragma unroll
        for (int bt=0;bt<4;bt++) sah[bt][n]=fmaxf(acc[bt],0.f);
    }
    __syncthreads();
    if (t<196){
        int bt=t/49, q=t-bt*49;
        float acc=0.f;
        for (int k=0;k<512;k++) acc+=sah[bt][k]*av_gw[k*49+q];
        gGA[(size_t)(b0+bt)*49+q]=acc;
    }
}

// ---------------- fully fused AVGA: one block per (b,t) ----------------
DEV void cvt4_(float4 v, f16x4& hv, f16x4& lv){
    hv[0]=(_Float16)v.x; lv[0]=(_Float16)(v.x-(float)hv[0]);
    hv[1]=(_Float16)v.y; lv[1]=(_Float16)(v.y-(float)hv[1]);
    hv[2]=(_Float16)v.z; lv[2]=(_Float16)(v.z-(float)hv[2]);
    hv[3]=(_Float16)v.w; lv[3]=(_Float16)(v.w-(float)hv[3]);
}

__global__ __launch_bounds__(256,3) void k_avga_fused(
    const float* __restrict__ video,
    const _Float16* __restrict__ Bh, const _Float16* __restrict__ Bl,
    const float* __restrict__ bias,
    const _Float16* __restrict__ Wh, const _Float16* __restrict__ Wl,
    const float* __restrict__ gGA, const float* __restrict__ hw,
    float* __restrict__ vT)
{
    __shared__ __align__(16) char smem[49152];
    // K loop:   sA dbuf [0,16384)
    // epilogue: vh per wave at 16384 + w*8192   [16384,49152)
    // reduce:   buf0 [0,16384), buf1 [16384,32768); szp@32768, salpha@33792
    int bt = blockIdx.x;
    int t = threadIdx.x;
    int lane = t & 63, w = t >> 6;
    int l16 = lane & 15, lq = lane >> 4;
    int lb = lane * 16;

    int am = t >> 3, ak = (t & 7) * 4;
    int aoff1 = ((am>>4)*4 + (ak>>3))*256 + (am&15)*16 + (ak&7)*2;
    int am2 = am + 32;
    int aoff2 = ((am2>>4)*4 + (ak>>3))*256 + (am2&15)*16 + (ak&7)*2;
    size_t r1 = (size_t)bt*49 + am;  if (r1 > 125439) r1 = 125439;
    size_t r2 = (size_t)bt*49 + am2; if (r2 > 125439) r2 = 125439;
    const float* Arow1 = video + r1*512 + ak;
    const float* Arow2 = video + r2*512 + ak;

    const f32x4 vzero = {0.f,0.f,0.f,0.f};
    f32x4 acc[4][8];
    #pragma unroll
    for (int p=0;p<4;p++)
        #pragma unroll
        for (int q=0;q<8;q++) acc[p][q] = vzero;

    float4 pa0, pa1;
    pa0 = *(const float4*)(Arow1);
    pa1 = *(const float4*)(Arow2);
    {
        f16x4 hv, lv;
        char* h = &smem[0];
        cvt4_(pa0, hv, lv);
        *(f16x4*)(h + aoff1) = hv; *(f16x4*)(h + 4096 + aoff1) = lv;
        cvt4_(pa1, hv, lv);
        *(f16x4*)(h + aoff2) = hv; *(f16x4*)(h + 4096 + aoff2) = lv;
    }
    __syncthreads();

    for (int kt = 0; kt < 16; ++kt){
        int cur = kt & 1;
        bool more = (kt < 15);
        if (more){
            pa0 = *(const float4*)(Arow1 + (kt+1)*32);
            pa1 = *(const float4*)(Arow2 + (kt+1)*32);
        }
        const char* aB = &smem[cur*8192];
        f16x8 ah[4], al[4];
        #pragma unroll
        for (int p=0;p<4;p++){
            ah[p] = *(const f16x8*)(aB + p*1024 + lb);
            al[p] = *(const f16x8*)(aB + 4096 + p*1024 + lb);
        }
        #pragma unroll
        for (int q=0;q<8;q++){
            size_t bo = (size_t)kt*16384 + (size_t)(w*8 + q)*512 + lane*8;
            f16x8 bh  = *(const f16x8*)(Bh + bo);
            f16x8 bl2 = *(const f16x8*)(Bl + bo);
            #pragma unroll
            for (int p=0;p<4;p++){
                acc[p][q] = MFMA16(ah[p], bh,  acc[p][q]);
                acc[p][q] = MFMA16(ah[p], bl2, acc[p][q]);
                acc[p][q] = MFMA16(al[p], bh,  acc[p][q]);
            }
        }
        if (more){
            char* h = &smem[(cur^1)*8192];
            f16x4 hv, lv;
            cvt4_(pa0, hv, lv);
            *(f16x4*)(h + aoff1) = hv; *(f16x4*)(h + 4096 + aoff1) = lv;
            cvt4_(pa1, hv, lv);
            *(f16x4*)(h + aoff2) = hv; *(f16x4*)(h + 4096 + aoff2) = lv;
        }
        __syncthreads();
    }

    // ---- epilogue: per-wave VH (bias+relu, f16 hi/lo) + content MFMA --
    float bv[8];
    #pragma unroll
    for (int q=0;q<8;q++) bv[q] = bias[w*128 + q*16 + l16];

    char* vh = &smem[16384 + w*8192];
    f32x4 cacc[4][4];
    #pragma unroll
    for (int p=0;p<4;p++)
        #pragma unroll
        for (int qf=0;qf<4;qf++) cacc[p][qf] = vzero;

    #pragma unroll
    for (int c=0;c<4;c++){
        #pragma unroll
        for (int p=0;p<4;p++)
            #pragma unroll
            for (int qq=0;qq<2;qq++){
                int q = c*2 + qq;
                int offbase = p*1024 + (qq*2 + (l16>>3))*256 + (l16&7)*2;
                #pragma unroll
                for (int r=0;r<4;r++){
                    float x = fmaxf(acc[p][q][r] + bv[q], 0.f);
                    _Float16 hh = (_Float16)x;
                    _Float16 ll = (_Float16)(x - (float)hh);
                    int off = offbase + (lq*4 + r)*16;
                    *(_Float16*)(vh + off)        = hh;
                    *(_Float16*)(vh + 4096 + off) = ll;
                }
            }
        int kbg = w*4 + c;
        f16x8 vhh[4], vhl[4];
        #pragma unroll
        for (int p=0;p<4;p++){
            vhh[p] = *(const f16x8*)(vh + p*1024 + lb);
            vhl[p] = *(const f16x8*)(vh + 4096 + p*1024 + lb);
        }
        #pragma unroll
        for (int qf=0;qf<4;qf++){
            size_t wo = (size_t)kbg*2048 + qf*512 + lane*8;
            f16x8 wh = *(const f16x8*)(Wh + wo);
            f16x8 wl = *(const f16x8*)(Wl + wo);
            #pragma unroll
            for (int p=0;p<4;p++){
                cacc[p][qf] = MFMA16(vhh[p], wh, cacc[p][qf]);
                cacc[p][qf] = MFMA16(vhh[p], wl, cacc[p][qf]);
                cacc[p][qf] = MFMA16(vhl[p], wh, cacc[p][qf]);
            }
        }
    }

    // ---- 2-buffer sequential content reduce ----
    __syncthreads();
    float* rbuf = (float*)&smem[(w&1)*16384];
    if (w < 2){
        #pragma unroll
        for (int p=0;p<4;p++)
            #pragma unroll
            for (int qf=0;qf<4;qf++)
                #pragma unroll
                for (int r=0;r<4;r++)
                    rbuf[(p*16 + lq*4 + r)*64 + qf*16 + l16] = cacc[p][qf][r];
    }
    __syncthreads();
    if (w >= 2){
        #pragma unroll
        for (int p=0;p<4;p++)
            #pragma unroll
            for (int qf=0;qf<4;qf++)
                #pragma unroll
                for (int r=0;r<4;r++)
                    rbuf[(p*16 + lq*4 + r)*64 + qf*16 + l16] += cacc[p][qf][r];
    }
    __syncthreads();

    // ---- z, softmax, weighted sum ----
    const float* cb0 = (const float*)&smem[0];
    const float* cb1 = (const float*)&smem[16384];
    float* szp    = (float*)&smem[32768];
    float* salpha = (float*)&smem[33792];
    if (t < 196){
        int p = t >> 2, ds = t & 3;
        float ga = gGA[(size_t)bt*49 + p];
        float part = 0.f;
        for (int q = ds*13; q < ds*13+13 && q < 49; q++)
            part += tanhf(cb0[p*64 + q] + cb1[p*64 + q] + ga) * hw[q];
        szp[t] = part;
    }
    __syncthreads();
    if (t < 64){
        float z = (t<49) ? (szp[t*4]+szp[t*4+1]+szp[t*4+2]+szp[t*4+3]) : -1e30f;
        float m = z;
        #pragma unroll
        for (int off=32; off; off>>=1) m = fmaxf(m, __shfl_xor(m, off));
        float e = (t<49)? expf(z - m) : 0.f;
        float s = e;
        #pragma unroll
        for (int off=32; off; off>>=1) s += __shfl_xor(s, off);
        salpha[t] = e / s;
    }
    __syncthreads();
    const float* vb = video + (size_t)bt*49*512;
    #pragma unroll
    for (int u=0;u<2;u++){
        int d = t + u*256;
        float a0 = 0.f;
        for (int p=0;p<49;p++) a0 += salpha[p] * vb[(size_t)p*512 + d];
        vT[(size_t)bt*512 + d] = a0;
    }
}

// ---------------- generic split-f16 MFMA GEMM --------------------------
// C[M,ldc] = op(A[M,lda] @ Wpk + bias). Tile MP*16 x NQ*64 (4 waves x NQ frags).
template<int MP, int NQ, bool BIAS, bool RELU>
__global__ __launch_bounds__(256) void k_gemm(
    const float* __restrict__ A, int lda,
    const _Float16* __restrict__ Wh, const _Float16* __restrict__ Wl,
    const float* __restrict__ bias,
    float* __restrict__ C, int ldc,
    int nkt, int Nfr)
{
    __shared__ __align__(16) char sA[2][MP*2048];   // hi MP*1024 | lo MP*1024
    int t = threadIdx.x, lane = t&63, w = t>>6;
    int l16 = lane&15, lq = lane>>4, lb = lane*16;
    int row0 = blockIdx.x * (MP*16);
    int nf0 = blockIdx.y * (4*NQ) + w*NQ;

    int am = t>>3, ak = (t&7)*4;     // MP=2: 32 rows x 8 k-threads
    int aoff = ((am>>4)*4 + (ak>>3))*256 + (am&15)*16 + (ak&7)*2;
    const float* Arow = A + (size_t)(row0+am)*lda + ak;

    const f32x4 vzero = {0.f,0.f,0.f,0.f};
    f32x4 acc[MP][NQ];
    #pragma unroll
    for (int p=0;p<MP;p++)
        #pragma unroll
        for (int q=0;q<NQ;q++) acc[p][q] = vzero;

    float4 pa = *(const float4*)(Arow);
    {
        f16x4 hv, lv;
        char* h = &sA[0][0];
        cvt4_(pa, hv, lv);
        *(f16x4*)(h + aoff) = hv; *(f16x4*)(h + MP*1024 + aoff) = lv;
    }
    __syncthreads();

    for (int kt = 0; kt < nkt; ++kt){
        int cur = kt & 1;
        bool more = (kt+1 < nkt);
        if (more) pa = *(const float4*)(Arow + (kt+1)*32);
        const char* aB = &sA[cur][0];
        f16x8 ah[MP], al[MP];
        #pragma unroll
        for (int p=0;p<MP;p++){
            ah[p] = *(const f16x8*)(aB + p*1024 + lb);
            al[p] = *(const f16x8*)(aB + MP*1024 + p*1024 + lb);
        }
        #pragma unroll
        for (int q=0;q<NQ;q++){
            size_t bo = ((size_t)kt*Nfr + nf0 + q)*512 + lane*8;
            f16x8 bh  = *(const f16x8*)(Wh + bo);
            f16x8 bl2 = *(const f16x8*)(Wl + bo);
            #pragma unroll
            for (int p=0;p<MP;p++){
                acc[p][q] = MFMA16(ah[p], bh,  acc[p][q]);
                acc[p][q] = MFMA16(ah[p], bl2, acc[p][q]);
                acc[p][q] = MFMA16(al[p], bh,  acc[p][q]);
            }
        }
        if (more){
            char* h = &sA[cur^1][0];
            f16x4 hv, lv;
            cvt4_(pa, hv, lv);
            *(f16x4*)(h + aoff) = hv; *(f16x4*)(h + MP*1024 + aoff) = lv;
        }
        __syncthreads();
    }

    #pragma unroll
    for (int q=0;q<NQ;q++){
        int n = (nf0+q)*16 + l16;
        float bv = BIAS ? bias[n] : 0.f;
        #pragma unroll
        for (int p=0;p<MP;p++){
            #pragma unroll
            for (int r=0;r<4;r++){
                float v = acc[p][q][r] + bv;
                if (RELU) v = fmaxf(v, 0.f);
                C[(size_t)(row0 + p*16 + lq*4 + r)*ldc + n] = v;
            }
        }
    }
}

// ---------------- persistent bidirectional LSTMs (256 blocks) ----------
__global__ __launch_bounds__(256) void k_lstm(
    const float* __restrict__ xpA, const float* __restrict__ xpV,
    const float* __restrict__ la_whh, const float* __restrict__ lv_whh,
    float* __restrict__ lstm_a, float* __restrict__ lstm_v)
{
    int blk = blockIdx.x;
    int c = blk >> 6;
    int chunk = blk & 63;
    int t = threadIdx.x;
    int j  = t & 127;
    int bh = t >> 7;
    const float* whh = ((c<2)? la_whh : lv_whh) + (size_t)(c&1)*128*512;
    const float* xpm = (c<2)? xpA : xpV;
    float* outp = (c<2)? lstm_a : lstm_v;
    int dir = c & 1;

    __shared__ float hbuf[4][128];
    float cc[2] = {0.f,0.f};
    for (int i=t;i<512;i+=256) ((float*)hbuf)[i] = 0.f;
    __syncthreads();

    for (int s=0; s<10; s++){
        int tt = dir ? (9-s) : s;
        float gi[2], gf[2], gg[2], go[2];
        #pragma unroll
        for (int b=0;b<2;b++){
            int gb = chunk*4 + bh*2 + b;
            const float* xrow = xpm + ((size_t)gb*10 + tt)*1024 + dir*512;
            gi[b]=xrow[j]; gf[b]=xrow[128+j]; gg[b]=xrow[256+j]; go[b]=xrow[384+j];
        }
        #pragma unroll 4
        for (int k=0;k<128;k++){
            float wi = whh[k*512 + j];
            float wf = whh[k*512 + 128 + j];
            float wg = whh[k*512 + 256 + j];
            float wo = whh[k*512 + 384 + j];
            #pragma unroll
            for (int b=0;b<2;b++){
                float hk = hbuf[bh*2+b][k];
                gi[b] += hk*wi; gf[b] += hk*wf; gg[b] += hk*wg; go[b] += hk*wo;
            }
        }
        __syncthreads();
        #pragma unroll
        for (int b=0;b<2;b++){
            float i_ = sigmoidf_(gi[b]);
            float f_ = sigmoidf_(gf[b]);
            float g_ = tanhf(gg[b]);
            float o_ = sigmoidf_(go[b]);
            cc[b] = f_*cc[b] + i_*g_;
            float h_ = o_*tanhf(cc[b]);
            hbuf[bh*2+b][j] = h_;
            int gb = chunk*4 + bh*2 + b;
            outp[((size_t)gb*10 + tt)*256 + dir*128 + j] = h_;
        }
        __syncthreads();
    }
}

// ---------------- per-sample PSP attention + psp outputs ---------------
__global__ __launch_bounds__(256) void k_att(
    const float* __restrict__ lstm_a, const float* __restrict__ lstm_v,
    const float* __restrict__ vb12, const float* __restrict__ ab12,
    const float* __restrict__ thrp,
    float* __restrict__ vpsp, float* __restrict__ apsp)
{
    int b = blockIdx.x, t = threadIdx.x;
    __shared__ float sV2[2560], sA1[2560], sV1[2560], sA2[2560];
    __shared__ float satt[100], s_v2a[100], s_a2v[100];
    size_t base = (size_t)b*2560;
    for (int i=t;i<2560;i+=256){
        int rr = i>>8, cc2 = i&255;
        size_t ro = (size_t)(b*10 + rr)*512;
        sV1[i]=vb12[ro + cc2]; sV2[i]=vb12[ro + 256 + cc2];
        sA1[i]=ab12[ro + cc2]; sA2[i]=ab12[ro + 256 + cc2];
    }
    __syncthreads();
    if (t < 100){
        int v = t/10, a = t - v*10;
        float acc=0.f;
        for (int k=0;k<256;k++) acc += sV2[v*256+k]*sA1[a*256+k];
        satt[t] = fmaxf(acc*(1.0f/16.0f), 0.f);
    }
    __syncthreads();
    float thr = thrp[0];
    if (t < 10){
        int v = t;
        float rs=0.f; for(int a=0;a<10;a++) rs += satt[v*10+a];
        float inv = 1.f/(rs+1e-8f);
        float tmp[10]; float rs2=0.f;
        for(int a=0;a<10;a++){ float x = satt[v*10+a]*inv; x = (x>thr)?x:0.f; tmp[a]=x; rs2+=x; }
        float inv2 = 1.f/(rs2+1e-8f);
        for(int a=0;a<10;a++) s_v2a[v*10+a] = tmp[a]*inv2;
    } else if (t>=16 && t<26){
        int a = t-16;
        float cs=0.f; for(int v=0;v<10;v++) cs += satt[v*10+a];
        float inv = 1.f/(cs+1e-8f);
        float tmp[10]; float cs2=0.f;
        for(int v=0;v<10;v++){ float x = satt[v*10+a]*inv; x=(x>thr)?x:0.f; tmp[v]=x; cs2+=x; }
        float inv2 = 1.f/(cs2+1e-8f);
        for(int v=0;v<10;v++) s_a2v[a*10+v] = tmp[v]*inv2;
    }
    __syncthreads();
    for (int v=0;v<10;v++){
        float acc = lstm_v[base + v*256 + t];
        #pragma unroll
        for (int a=0;a<10;a++) acc += s_v2a[v*10+a]*sA2[a*256+t];
        vpsp[base + v*256 + t] = acc;
    }
    for (int a=0;a<10;a++){
        float acc = lstm_a[base + a*256 + t];
        #pragma unroll
        for (int v=0;v<10;v++) acc += s_a2v[a*10+v]*sV1[v*256+t];
        apsp[base + a*256 + t] = acc;
    }
}

// ---------------- final: LN + fuse + cosine + MLP, 8 bt/block ----------
__global__ __launch_bounds__(256) void k_fin(
    const float* __restrict__ vrl, const float* __restrict__ arl,
    const float* __restrict__ ln_g, const float* __restrict__ ln_b,
    const float* __restrict__ L1w, const float* __restrict__ L2w,
    float* __restrict__ dout)
{
    int b0 = blockIdx.x*8;
    int t = threadIdx.x, w = t>>6, lane = t&63;
    __shared__ float sfu[4][256];
    __shared__ float s64b[4][64];
    int c0 = lane*4;
    int bt0 = w*2;
    float4 g4 = *(const float4*)&ln_g[c0];
    float4 b4 = *(const float4*)&ln_b[c0];
    float gv[4]={g4.x,g4.y,g4.z,g4.w}, bb[4]={b4.x,b4.y,b4.z,b4.w};

    for (int h=0;h<2;h++){
        int row = b0 + bt0 + h;
        float4 xv4 = *(const float4*)&vrl[(size_t)row*256 + c0];
        float4 xa4 = *(const float4*)&arl[(size_t)row*256 + c0];
        float xv[4]={xv4.x,xv4.y,xv4.z,xv4.w}, xa[4]={xa4.x,xa4.y,xa4.z,xa4.w};
        float s1 = wred64(xv[0]+xv[1]+xv[2]+xv[3]);
        float s2 = wred64(xv[0]*xv[0]+xv[1]*xv[1]+xv[2]*xv[2]+xv[3]*xv[3]);
        float mu = s1*(1.f/256.f);
        float var = s2*(1.f/256.f) - mu*mu;
        float rs = 1.f/sqrtf(var+1e-6f);
        float vln[4];
        #pragma unroll
        for (int jj=0;jj<4;jj++) vln[jj] = (xv[jj]-mu)*rs*gv[jj]+bb[jj];
        s1 = wred64(xa[0]+xa[1]+xa[2]+xa[3]);
        s2 = wred64(xa[0]*xa[0]+xa[1]*xa[1]+xa[2]*xa[2]+xa[3]*xa[3]);
        mu = s1*(1.f/256.f);
        var = s2*(1.f/256.f) - mu*mu;
        rs = 1.f/sqrtf(var+1e-6f);
        float aln[4];
        #pragma unroll
        for (int jj=0;jj<4;jj++) aln[jj] = (xa[jj]-mu)*rs*gv[jj]+bb[jj];

        float fu[4];
        #pragma unroll
        for (int jj=0;jj<4;jj++){ fu[jj] = 0.5f*(vln[jj]+aln[jj]); dout[(size_t)row*256 + c0 + jj] = fu[jj]; }

        float nv2 = wred64(vln[0]*vln[0]+vln[1]*vln[1]+vln[2]*vln[2]+vln[3]*vln[3]);
        float na2 = wred64(aln[0]*aln[0]+aln[1]*aln[1]+aln[2]*aln[2]+aln[3]*aln[3]);
        float dva = wred64(vln[0]*aln[0]+vln[1]*aln[1]+vln[2]*aln[2]+vln[3]*aln[3]);
        if (lane==0){
            float nv = fmaxf(sqrtf(nv2), 1e-12f);
            float na = fmaxf(sqrtf(na2), 1e-12f);
            dout[729600 + row] = dva/(nv*na);
        }
        *(float4*)&sfu[w][c0] = make_float4(fu[0],fu[1],fu[2],fu[3]);
        float acc = 0.f;
        for (int k4=0;k4<64;k4++){
            float4 f4 = *(const float4*)&sfu[w][k4*4];
            acc += f4.x*L1w[(k4*4)*64+lane] + f4.y*L1w[(k4*4+1)*64+lane]
                 + f4.z*L1w[(k4*4+2)*64+lane] + f4.w*L1w[(k4*4+3)*64+lane];
        }
        s64b[w][lane] = fmaxf(acc, 0.f);
        if (lane < 29){
            float acc2 = 0.f;
            #pragma unroll
            for (int k=0;k<64;k++) acc2 += s64b[w][k]*L2w[k*29+lane];
            dout[655360 + (size_t)row*29 + lane] = acc2;
        }
    }
}

// =======================================================================
extern "C" void kernel_launch(void* const* d_in, const int* in_sizes, int n_in,
                              void* d_out, int out_size, void* d_ws, size_t ws_size,
                              hipStream_t stream) {
    const float* audio  = (const float*)d_in[0];
    const float* video  = (const float*)d_in[1];
    const float* thrp   = (const float*)d_in[2];
    const float* fa_w1  = (const float*)d_in[3];
    const float* fa_w2  = (const float*)d_in[4];
    const float* av_aw  = (const float*)d_in[5];
    const float* av_ab  = (const float*)d_in[6];
    const float* av_vw  = (const float*)d_in[7];
    const float* av_vb  = (const float*)d_in[8];
    const float* av_v2w = (const float*)d_in[9];
    const float* av_gw  = (const float*)d_in[10];
    const float* av_hw  = (const float*)d_in[11];
    const float* fv_w1  = (const float*)d_in[12];
    const float* fv_w2  = (const float*)d_in[13];
    const float* la_wih = (const float*)d_in[14];
    const float* la_whh = (const float*)d_in[15];
    const float* la_b   = (const float*)d_in[16];
    const float* lv_wih = (const float*)d_in[17];
    const float* lv_whh = (const float*)d_in[18];
    const float* lv_b   = (const float*)d_in[19];
    const float* vL1    = (const float*)d_in[20];
    const float* vL2    = (const float*)d_in[21];
    const float* aL1    = (const float*)d_in[22];
    const float* aL2    = (const float*)d_in[23];
    const float* vfc    = (const float*)d_in[24];
    const float* afc    = (const float*)d_in[25];
    const float* ln_g   = (const float*)d_in[26];
    const float* ln_b   = (const float*)d_in[27];
    const float* L1w    = (const float*)d_in[28];
    const float* L2w    = (const float*)d_in[29];
    float* dout = (float*)d_out;
    float* ws = (float*)d_ws;

    // workspace layout (float offsets)
    float* faW  = ws;                 // 16384
    float* fvW  = ws + 16384;         // 65536
    float* fa   = ws + 81920;         // 327680
    float* gGA  = ws + 409600;        // 125440
    float* vT   = ws + 535040;        // 1310720
    float* xpA  = ws + 2173440;       // 2621440
    float* xpV  = ws + 4794880;       // 2621440
    float* la   = ws + 7416320;       // 655360
    float* lv   = ws + 8071680;       // 655360
    float* vb12 = ws + 8727040;       // 1310720
    float* ab12 = ws + 10037760;      // 1310720
    float* vpsp = ws + 11348480;      // 655360
    float* apsp = ws + 12003840;      // 655360
    _Float16* Bh = (_Float16*)(ws + 12659200);
    _Float16* Bl = (_Float16*)(ws + 12790272);
    _Float16* Wh = (_Float16*)(ws + 12921344);
    _Float16* Wl = (_Float16*)(ws + 12937728);
    _Float16* PKfv_h = (_Float16*)(ws + 12954112);
    _Float16* PKfv_l = (_Float16*)(ws + 12986880);
    _Float16* PKxa_h = (_Float16*)(ws + 13019648);
    _Float16* PKxa_l = (_Float16*)(ws + 13085184);
    _Float16* PKxv_h = (_Float16*)(ws + 13150720);
    _Float16* PKxv_l = (_Float16*)(ws + 13216256);
    _Float16* PKvl_h = (_Float16*)(ws + 13281792);
    _Float16* PKvl_l = (_Float16*)(ws + 13347328);
    _Float16* PKal_h = (_Float16*)(ws + 13412864);
    _Float16* PKal_l = (_Float16*)(ws + 13478400);
    _Float16* PKvf_h = (_Float16*)(ws + 13543936);
    _Float16* PKvf_l = (_Float16*)(ws + 13576704);
    _Float16* PKaf_h = (_Float16*)(ws + 13609472);
    _Float16* PKaf_l = (_Float16*)(ws + 13642240);
    float* vfea = ws + 13675008;      // 327680
    float* vrl  = ws + 14002688;      // 655360
    float* arl  = ws + 14658048;      // 655360 -> end 15313408

    k_prep<<<1472, 256, 0, stream>>>(fa_w1, fa_w2, faW, fv_w1, fv_w2, fvW,
                                     av_vw, Bh, Bl, av_v2w, Wh, Wl);
    k_prep2<<<2816, 256, 0, stream>>>(fvW, la_wih, lv_wih, vL1, vL2, aL1, aL2,
                                      vfc, afc,
                                      PKfv_h, PKfv_l, PKxa_h, PKxa_l, PKxv_h, PKxv_l,
                                      PKvl_h, PKvl_l, PKal_h, PKal_l,
                                      PKvf_h, PKvf_l, PKaf_h, PKaf_l);
    k_faga<<<640, 256, 0, stream>>>(audio, faW, av_aw, av_ab, av_gw, fa, gGA);
    k_avga_fused<<<2560, 256, 0, stream>>>(video, Bh, Bl, av_vb, Wh, Wl,
                                           gGA, av_hw, vT);
    // vfea = vT @ fvW  [2560,512]x[512,128]
    k_gemm<2,2,false,false><<<dim3(80,1), 256, 0, stream>>>(
        vT, 512, PKfv_h, PKfv_l, nullptr, vfea, 128, 16, 8);
    // xpA = fa @ [wihA_f|wihA_b] + la_b   [2560,128]x[128,1024]
    k_gemm<2,4,true,false><<<dim3(80,4), 256, 0, stream>>>(
        fa, 128, PKxa_h, PKxa_l, la_b, xpA, 1024, 4, 64);
    // xpV = vfea @ [wihV_f|wihV_b] + lv_b
    k_gemm<2,4,true,false><<<dim3(80,4), 256, 0, stream>>>(
        vfea, 128, PKxv_h, PKxv_l, lv_b, xpV, 1024, 4, 64);
    k_lstm<<<256, 256, 0, stream>>>(xpA, xpV, la_whh, lv_whh, la, lv);
    // vb12 = relu(lv @ [vL1|vL2])   [2560,256]x[256,512]
    k_gemm<2,4,false,true><<<dim3(80,2), 256, 0, stream>>>(
        lv, 256, PKvl_h, PKvl_l, nullptr, vb12, 512, 8, 32);
    // ab12 = relu(la @ [aL1|aL2])
    k_gemm<2,4,false,true><<<dim3(80,2), 256, 0, stream>>>(
        la, 256, PKal_h, PKal_l, nullptr, ab12, 512, 8, 32);
    k_att<<<256, 256, 0, stream>>>(la, lv, vb12, ab12, thrp, vpsp, apsp);
    // vrl = relu(vpsp @ vfc), arl = relu(apsp @ afc)
    k_gemm<2,4,false,true><<<dim3(80,1), 256, 0, stream>>>(
        vpsp, 256, PKvf_h, PKvf_l, nullptr, vrl, 256, 8, 16);
    k_gemm<2,4,false,true><<<dim3(80,1), 256, 0, stream>>>(
        apsp, 256, PKaf_h, PKaf_l, nullptr, arl, 256, 8, 16);
    k_fin<<<320, 256, 0, stream>>>(vrl, arl, ln_g, ln_b, L1w, L2w, dout);
}

// Round 7
// 758.411 us; speedup vs baseline: 1.5982x; 1.5982x over previous
//
#include <hip/hip_runtime.h>
#include <math.h>

#define DEV __device__ __forceinline__

typedef _Float16 f16x8 __attribute__((ext_vector_type(8)));
typedef _Float16 f16x4 __attribute__((ext_vector_type(4)));
typedef float    f32x4 __attribute__((ext_vector_type(4)));

DEV float sigmoidf_(float x){ return 1.0f/(1.0f + expf(-x)); }

DEV float wred64(float x){
    #pragma unroll
    for (int off=32; off; off>>=1) x += __shfl_xor(x, off);
    return x;
}

#define MFMA16(a,b,c) __builtin_amdgcn_mfma_f32_16x16x32_f16(a,b,c,0,0,0)

// ---------------- prep: faW, fvW, bpack(av_vw), bpack2(v2w) ------------
__global__ __launch_bounds__(256) void k_prep(
    const float* __restrict__ fa_w1, const float* __restrict__ fa_w2, float* __restrict__ faW,
    const float* __restrict__ fv_w1, const float* __restrict__ fv_w2, float* __restrict__ fvW,
    const float* __restrict__ av_vw, _Float16* __restrict__ Bh, _Float16* __restrict__ Bl,
    const float* __restrict__ v2w, _Float16* __restrict__ Wh, _Float16* __restrict__ Wl)
{
    int bid = blockIdx.x, t = threadIdx.x;
    if (bid < 64){
        int idx = bid*256+t; int m = idx>>7, n = idx&127;
        float acc=0.f;
        for (int k=0;k<256;k++) acc += fa_w1[m*256+k]*fa_w2[k*128+n];
        faW[idx]=acc;
    } else if (bid < 320){
        int idx = (bid-64)*256+t; int m = idx>>7, n = idx&127;
        float acc=0.f;
        for (int k=0;k<256;k++) acc += fv_w1[m*256+k]*fv_w2[k*128+n];
        fvW[idx]=acc;
    } else if (bid < 1344){
        int o = (bid-320)*256+t;
        int j = o & 7, l16 = (o>>3)&15, kg = (o>>7)&3, nf = (o>>9)&31, kt = o>>14;
        int k = kt*32 + kg*8 + j, n = nf*16 + l16;
        float x = av_vw[(size_t)k*512 + n];
        _Float16 h = (_Float16)x;
        Bh[o] = h; Bl[o] = (_Float16)(x - (float)h);
    } else {
        int o = (bid-1344)*256+t;
        int j = o & 7, l16 = (o>>3)&15, kg = (o>>7)&3, qf = (o>>9)&3, kbg = o>>11;
        int k = kbg*32 + kg*8 + j, q = qf*16 + l16;
        float x = (q < 49) ? v2w[(size_t)k*49 + q] : 0.f;
        _Float16 h = (_Float16)x;
        Wh[o] = h; Wl[o] = (_Float16)(x - (float)h);
    }
}

// ---------------- prep2: pack fvW / la_wih / lv_wih --------------------
DEV void packone(const float* __restrict__ src, int N, int NfrTot, int nfOff,
                 _Float16* __restrict__ Dh, _Float16* __restrict__ Dl, int o){
    int j = o&7, l16 = (o>>3)&15, kg = (o>>7)&3;
    int rest = o>>9;
    int nfl = rest % (N>>4), kt = rest / (N>>4);
    int k = kt*32 + kg*8 + j, n = nfl*16 + l16;
    float x = src[(size_t)k*N + n];
    _Float16 h = (_Float16)x;
    size_t d = ((size_t)kt*NfrTot + nfOff + nfl)*512 + kg*128 + l16*8 + j;
    Dh[d] = h; Dl[d] = (_Float16)(x - (float)h);
}

__global__ __launch_bounds__(256) void k_prep2(
    const float* __restrict__ fvW,
    const float* __restrict__ la_wih, const float* __restrict__ lv_wih,
    _Float16* PKfv_h, _Float16* PKfv_l,
    _Float16* PKxv_h, _Float16* PKxv_l)
{
    int seg = blockIdx.x >> 8;
    int o = (blockIdx.x & 255)*256 + threadIdx.x;   // [0,65536)
    switch(seg){
    case 0:  packone(fvW,            128,  8,  0, PKfv_h, PKfv_l, o); break;
    case 1:  packone(lv_wih,         512, 64,  0, PKxv_h, PKxv_l, o); break;
    default: packone(lv_wih+65536,   512, 64, 32, PKxv_h, PKxv_l, o); break;
    }
    (void)la_wih;
}

// ---------------- fused fa + a_h + ga + xpA, 4 bt per block ------------
__global__ __launch_bounds__(256) void k_faga2(
    const float* __restrict__ audio, const float* __restrict__ faW,
    const float* __restrict__ av_aw, const float* __restrict__ av_ab,
    const float* __restrict__ av_gw,
    const float* __restrict__ la_wih, const float* __restrict__ la_b,
    float* __restrict__ gGA, float* __restrict__ xpA)
{
    int b0 = blockIdx.x*4; int t = threadIdx.x;
    __shared__ float sau[4][128], sfa[4][128], sah[4][512];
    for (int i=t;i<512;i+=256){ int bt=i>>7,k=i&127; sau[bt][k]=audio[(size_t)(b0+bt)*128+k]; }
    __syncthreads();
    for (int u=0;u<2;u++){
        int i=t+u*256, bt=i>>7, n=i&127;
        float acc=0.f;
        for (int k4=0;k4<32;k4++){
            float4 x4=*(const float4*)&sau[bt][k4*4];
            acc+=x4.x*faW[(k4*4)*128+n]+x4.y*faW[(k4*4+1)*128+n]
                +x4.z*faW[(k4*4+2)*128+n]+x4.w*faW[(k4*4+3)*128+n];
        }
        sfa[bt][n]=acc;
    }
    __syncthreads();
    for (int u=0;u<2;u++){
        int n=t+u*256;
        float bv=av_ab[n];
        float acc[4]={bv,bv,bv,bv};
        for (int k4=0;k4<32;k4++){
            float w0=av_aw[(k4*4)*512+n], w1=av_aw[(k4*4+1)*512+n],
                  w2=av_aw[(k4*4+2)*512+n], w3=av_aw[(k4*4+3)*512+n];
            #pragma unroll
            for (int bt=0;bt<4;bt++){
                float4 x4=*(const float4*)&sfa[bt][k4*4];
                acc[bt]+=x4.x*w0+x4.y*w1+x4.z*w2+x4.w*w3;
            }
        }
        #pragma unroll
        for (int bt=0;bt<4;bt++) sah[bt][n]=fmaxf(acc[bt],0.f);
    }
    __syncthreads();
    if (t<196){
        int bt=t/49, q=t-bt*49;
        float acc=0.f;
        for (int k=0;k<512;k++) acc+=sah[bt][k]*av_gw[k*49+q];
        gGA[(size_t)(b0+bt)*49+q]=acc;
    }
    // xpA = fa @ [wihA_f | wihA_b] + la_b   (sfa unchanged since its sync)
    for (int u=0;u<4;u++){
        int n = t + u*256;
        int dir = n >> 9, g = n & 511;
        const float* W = la_wih + (size_t)dir*65536;
        float bvv = la_b[dir*512 + g];
        float acc[4] = {bvv,bvv,bvv,bvv};
        for (int k4=0;k4<32;k4++){
            float w0=W[(k4*4+0)*512+g], w1=W[(k4*4+1)*512+g],
                  w2=W[(k4*4+2)*512+g], w3=W[(k4*4+3)*512+g];
            #pragma unroll
            for (int bt=0;bt<4;bt++){
                float4 x4=*(const float4*)&sfa[bt][k4*4];
                acc[bt]+=x4.x*w0+x4.y*w1+x4.z*w2+x4.w*w3;
            }
        }
        #pragma unroll
        for (int bt=0;bt<4;bt++)
            xpA[((size_t)(b0+bt))*1024 + n] = acc[bt];
    }
}

// ---------------- fully fused AVGA: one block per (b,t) ----------------
DEV void cvt4_(float4 v, f16x4& hv, f16x4& lv){
    hv[0]=(_Float16)v.x; lv[0]=(_Float16)(v.x-(float)hv[0]);
    hv[1]=(_Float16)v.y; lv[1]=(_Float16)(v.y-(float)hv[1]);
    hv[2]=(_Float16)v.z; lv[2]=(_Float16)(v.z-(float)hv[2]);
    hv[3]=(_Float16)v.w; lv[3]=(_Float16)(v.w-(float)hv[3]);
}

__global__ __launch_bounds__(256,2) void k_avga_fused(
    const float* __restrict__ video,
    const _Float16* __restrict__ Bh, const _Float16* __restrict__ Bl,
    const float* __restrict__ bias,
    const _Float16* __restrict__ Wh, const _Float16* __restrict__ Wl,
    const float* __restrict__ gGA, const float* __restrict__ hw,
    float* __restrict__ vT)
{
    __shared__ __align__(16) char smem[67072];
    int bt = blockIdx.x;
    int t = threadIdx.x;
    int lane = t & 63, w = t >> 6;
    int l16 = lane & 15, lq = lane >> 4;
    int lb = lane * 16;

    int am = t >> 3, ak = (t & 7) * 4;
    int aoff1 = ((am>>4)*4 + (ak>>3))*256 + (am&15)*16 + (ak&7)*2;
    int am2 = am + 32;
    int aoff2 = ((am2>>4)*4 + (ak>>3))*256 + (am2&15)*16 + (ak&7)*2;
    size_t r1 = (size_t)bt*49 + am;  if (r1 > 125439) r1 = 125439;
    size_t r2 = (size_t)bt*49 + am2; if (r2 > 125439) r2 = 125439;
    const float* Arow1 = video + r1*512 + ak;
    const float* Arow2 = video + r2*512 + ak;

    const f32x4 vzero = {0.f,0.f,0.f,0.f};
    f32x4 acc[4][8];
    #pragma unroll
    for (int p=0;p<4;p++)
        #pragma unroll
        for (int q=0;q<8;q++) acc[p][q] = vzero;

    float4 pa0, pa1;
    pa0 = *(const float4*)(Arow1);
    pa1 = *(const float4*)(Arow2);
    {
        f16x4 hv, lv;
        char* h = &smem[0];
        cvt4_(pa0, hv, lv);
        *(f16x4*)(h + aoff1) = hv; *(f16x4*)(h + 4096 + aoff1) = lv;
        cvt4_(pa1, hv, lv);
        *(f16x4*)(h + aoff2) = hv; *(f16x4*)(h + 4096 + aoff2) = lv;
    }
    __syncthreads();

    for (int kt = 0; kt < 16; ++kt){
        int cur = kt & 1;
        bool more = (kt < 15);
        if (more){
            pa0 = *(const float4*)(Arow1 + (kt+1)*32);
            pa1 = *(const float4*)(Arow2 + (kt+1)*32);
        }
        const char* aB = &smem[cur*8192];
        f16x8 ah[4], al[4];
        #pragma unroll
        for (int p=0;p<4;p++){
            ah[p] = *(const f16x8*)(aB + p*1024 + lb);
            al[p] = *(const f16x8*)(aB + 4096 + p*1024 + lb);
        }
        #pragma unroll
        for (int q=0;q<8;q++){
            size_t bo = (size_t)kt*16384 + (size_t)(w*8 + q)*512 + lane*8;
            f16x8 bh  = *(const f16x8*)(Bh + bo);
            f16x8 bl2 = *(const f16x8*)(Bl + bo);
            #pragma unroll
            for (int p=0;p<4;p++){
                acc[p][q] = MFMA16(ah[p], bh,  acc[p][q]);
                acc[p][q] = MFMA16(ah[p], bl2, acc[p][q]);
                acc[p][q] = MFMA16(al[p], bh,  acc[p][q]);
            }
        }
        if (more){
            char* h = &smem[(cur^1)*8192];
            f16x4 hv, lv;
            cvt4_(pa0, hv, lv);
            *(f16x4*)(h + aoff1) = hv; *(f16x4*)(h + 4096 + aoff1) = lv;
            cvt4_(pa1, hv, lv);
            *(f16x4*)(h + aoff2) = hv; *(f16x4*)(h + 4096 + aoff2) = lv;
        }
        __syncthreads();
    }

    // ---- epilogue: per-wave VH (bias+relu, f16 hi/lo) + content MFMA --
    float bv[8];
    #pragma unroll
    for (int q=0;q<8;q++) bv[q] = bias[w*128 + q*16 + l16];

    char* vh = &smem[16384 + w*8192];
    f32x4 cacc[4][4];
    #pragma unroll
    for (int p=0;p<4;p++)
        #pragma unroll
        for (int qf=0;qf<4;qf++) cacc[p][qf] = vzero;

    #pragma unroll
    for (int c=0;c<4;c++){
        #pragma unroll
        for (int p=0;p<4;p++)
            #pragma unroll
            for (int qq=0;qq<2;qq++){
                int q = c*2 + qq;
                int offbase = p*1024 + (qq*2 + (l16>>3))*256 + (l16&7)*2;
                #pragma unroll
                for (int r=0;r<4;r++){
                    float x = fmaxf(acc[p][q][r] + bv[q], 0.f);
                    _Float16 hh = (_Float16)x;
                    _Float16 ll = (_Float16)(x - (float)hh);
                    int off = offbase + (lq*4 + r)*16;
                    *(_Float16*)(vh + off)        = hh;
                    *(_Float16*)(vh + 4096 + off) = ll;
                }
            }
        int kbg = w*4 + c;
        f16x8 vhh[4], vhl[4];
        #pragma unroll
        for (int p=0;p<4;p++){
            vhh[p] = *(const f16x8*)(vh + p*1024 + lb);
            vhl[p] = *(const f16x8*)(vh + 4096 + p*1024 + lb);
        }
        #pragma unroll
        for (int qf=0;qf<4;qf++){
            size_t wo = (size_t)kbg*2048 + qf*512 + lane*8;
            f16x8 wh = *(const f16x8*)(Wh + wo);
            f16x8 wl = *(const f16x8*)(Wl + wo);
            #pragma unroll
            for (int p=0;p<4;p++){
                cacc[p][qf] = MFMA16(vhh[p], wh, cacc[p][qf]);
                cacc[p][qf] = MFMA16(vhh[p], wl, cacc[p][qf]);
                cacc[p][qf] = MFMA16(vhl[p], wh, cacc[p][qf]);
            }
        }
    }

    // ---- cross-wave content reduce ----
    __syncthreads();
    float* pw = (float*)&smem[w*16384];
    #pragma unroll
    for (int p=0;p<4;p++)
        #pragma unroll
        for (int qf=0;qf<4;qf++)
            #pragma unroll
            for (int r=0;r<4;r++)
                pw[(p*16 + lq*4 + r)*64 + qf*16 + l16] = cacc[p][qf][r];
    __syncthreads();
    float* cb = (float*)&smem[0];
    for (int i=t; i<4096; i+=256)
        cb[i] = cb[i] + cb[4096+i] + cb[8192+i] + cb[12288+i];
    __syncthreads();

    // ---- z, softmax, weighted sum ----
    float* szp    = (float*)&smem[65536];
    float* salpha = (float*)&smem[66560];
    if (t < 196){
        int p = t >> 2, ds = t & 3;
        float ga = gGA[(size_t)bt*49 + p];
        float part = 0.f;
        for (int q = ds*13; q < ds*13+13 && q < 49; q++)
            part += tanhf(cb[p*64 + q] + ga) * hw[q];
        szp[t] = part;
    }
    __syncthreads();
    if (t < 64){
        float z = (t<49) ? (szp[t*4]+szp[t*4+1]+szp[t*4+2]+szp[t*4+3]) : -1e30f;
        float m = z;
        #pragma unroll
        for (int off=32; off; off>>=1) m = fmaxf(m, __shfl_xor(m, off));
        float e = (t<49)? expf(z - m) : 0.f;
        float s = e;
        #pragma unroll
        for (int off=32; off; off>>=1) s += __shfl_xor(s, off);
        salpha[t] = e / s;
    }
    __syncthreads();
    const float* vb = video + (size_t)bt*49*512;
    #pragma unroll
    for (int u=0;u<2;u++){
        int d = t + u*256;
        float a0 = 0.f;
        for (int p=0;p<49;p++) a0 += salpha[p] * vb[(size_t)p*512 + d];
        vT[(size_t)bt*512 + d] = a0;
    }
}

// ---------------- generic split-f16 MFMA GEMM --------------------------
template<int MP, int NQ, bool BIAS, bool RELU>
__global__ __launch_bounds__(256) void k_gemm(
    const float* __restrict__ A, int lda,
    const _Float16* __restrict__ Wh, const _Float16* __restrict__ Wl,
    const float* __restrict__ bias,
    float* __restrict__ C, int ldc,
    int nkt, int Nfr)
{
    __shared__ __align__(16) char sA[2][MP*2048];
    int t = threadIdx.x, lane = t&63, w = t>>6;
    int l16 = lane&15, lq = lane>>4, lb = lane*16;
    int row0 = blockIdx.x * (MP*16);
    int nf0 = blockIdx.y * (4*NQ) + w*NQ;

    int am = t>>3, ak = (t&7)*4;
    int aoff = ((am>>4)*4 + (ak>>3))*256 + (am&15)*16 + (ak&7)*2;
    const float* Arow = A + (size_t)(row0+am)*lda + ak;

    const f32x4 vzero = {0.f,0.f,0.f,0.f};
    f32x4 acc[MP][NQ];
    #pragma unroll
    for (int p=0;p<MP;p++)
        #pragma unroll
        for (int q=0;q<NQ;q++) acc[p][q] = vzero;

    float4 pa = *(const float4*)(Arow);
    {
        f16x4 hv, lv;
        char* h = &sA[0][0];
        cvt4_(pa, hv, lv);
        *(f16x4*)(h + aoff) = hv; *(f16x4*)(h + MP*1024 + aoff) = lv;
    }
    __syncthreads();

    for (int kt = 0; kt < nkt; ++kt){
        int cur = kt & 1;
        bool more = (kt+1 < nkt);
        if (more) pa = *(const float4*)(Arow + (kt+1)*32);
        const char* aB = &sA[cur][0];
        f16x8 ah[MP], al[MP];
        #pragma unroll
        for (int p=0;p<MP;p++){
            ah[p] = *(const f16x8*)(aB + p*1024 + lb);
            al[p] = *(const f16x8*)(aB + MP*1024 + p*1024 + lb);
        }
        #pragma unroll
        for (int q=0;q<NQ;q++){
            size_t bo = ((size_t)kt*Nfr + nf0 + q)*512 + lane*8;
            f16x8 bh  = *(const f16x8*)(Wh + bo);
            f16x8 bl2 = *(const f16x8*)(Wl + bo);
            #pragma unroll
            for (int p=0;p<MP;p++){
                acc[p][q] = MFMA16(ah[p], bh,  acc[p][q]);
                acc[p][q] = MFMA16(ah[p], bl2, acc[p][q]);
                acc[p][q] = MFMA16(al[p], bh,  acc[p][q]);
            }
        }
        if (more){
            char* h = &sA[cur^1][0];
            f16x4 hv, lv;
            cvt4_(pa, hv, lv);
            *(f16x4*)(h + aoff) = hv; *(f16x4*)(h + MP*1024 + aoff) = lv;
        }
        __syncthreads();
    }

    #pragma unroll
    for (int q=0;q<NQ;q++){
        int n = (nf0+q)*16 + l16;
        float bv = BIAS ? bias[n] : 0.f;
        #pragma unroll
        for (int p=0;p<MP;p++){
            #pragma unroll
            for (int r=0;r<4;r++){
                float v = acc[p][q][r] + bv;
                if (RELU) v = fmaxf(v, 0.f);
                C[(size_t)(row0 + p*16 + lq*4 + r)*ldc + n] = v;
            }
        }
    }
}

// ---------------- persistent bidirectional LSTMs (256 blocks) ----------
__global__ __launch_bounds__(256) void k_lstm(
    const float* __restrict__ xpA, const float* __restrict__ xpV,
    const float* __restrict__ la_whh, const float* __restrict__ lv_whh,
    float* __restrict__ lstm_a, float* __restrict__ lstm_v)
{
    int blk = blockIdx.x;
    int c = blk >> 6;
    int chunk = blk & 63;
    int t = threadIdx.x;
    int j  = t & 127;
    int bh = t >> 7;
    const float* whh = ((c<2)? la_whh : lv_whh) + (size_t)(c&1)*128*512;
    const float* xpm = (c<2)? xpA : xpV;
    float* outp = (c<2)? lstm_a : lstm_v;
    int dir = c & 1;

    __shared__ float hbuf[4][128];
    float cc[2] = {0.f,0.f};
    for (int i=t;i<512;i+=256) ((float*)hbuf)[i] = 0.f;
    __syncthreads();

    for (int s=0; s<10; s++){
        int tt = dir ? (9-s) : s;
        float gi[2], gf[2], gg[2], go[2];
        #pragma unroll
        for (int b=0;b<2;b++){
            int gb = chunk*4 + bh*2 + b;
            const float* xrow = xpm + ((size_t)gb*10 + tt)*1024 + dir*512;
            gi[b]=xrow[j]; gf[b]=xrow[128+j]; gg[b]=xrow[256+j]; go[b]=xrow[384+j];
        }
        #pragma unroll 4
        for (int k=0;k<128;k++){
            float wi = whh[k*512 + j];
            float wf = whh[k*512 + 128 + j];
            float wg = whh[k*512 + 256 + j];
            float wo = whh[k*512 + 384 + j];
            #pragma unroll
            for (int b=0;b<2;b++){
                float hk = hbuf[bh*2+b][k];
                gi[b] += hk*wi; gf[b] += hk*wf; gg[b] += hk*wg; go[b] += hk*wo;
            }
        }
        __syncthreads();
        #pragma unroll
        for (int b=0;b<2;b++){
            float i_ = sigmoidf_(gi[b]);
            float f_ = sigmoidf_(gf[b]);
            float g_ = tanhf(gg[b]);
            float o_ = sigmoidf_(go[b]);
            cc[b] = f_*cc[b] + i_*g_;
            float h_ = o_*tanhf(cc[b]);
            hbuf[bh*2+b][j] = h_;
            int gb = chunk*4 + bh*2 + b;
            outp[((size_t)gb*10 + tt)*256 + dir*128 + j] = h_;
        }
        __syncthreads();
    }
}

// ---------------- per-sample mega tail: branches+att+psp+fc+LN+MLP -----
__global__ __launch_bounds__(256) void k_tail(
    const float* __restrict__ lstm_a, const float* __restrict__ lstm_v,
    const float* __restrict__ vL1, const float* __restrict__ vL2,
    const float* __restrict__ aL1, const float* __restrict__ aL2,
    const float* __restrict__ vfc, const float* __restrict__ afc,
    const float* __restrict__ thrp,
    const float* __restrict__ ln_g, const float* __restrict__ ln_b,
    const float* __restrict__ L1w, const float* __restrict__ L2w,
    float* __restrict__ dout)
{
    int b = blockIdx.x, t = threadIdx.x;
    int lane = t & 63, w = t >> 6;
    __shared__ float sla[10][256], slv[10][256];
    __shared__ float sb1v[10][256], sb2v[10][256], sb1a[10][256], sb2a[10][256];
    __shared__ float spv[10][256], spa[10][256];
    __shared__ float sfu[10][256];
    __shared__ float s64[10][64];
    __shared__ float satt[100], s_v2a[100], s_a2v[100];
    __shared__ float sredp[160];   // [10][4 vals][4 waves]
    __shared__ float scos[120];    // [10][3 vals][4 waves]

    size_t base = (size_t)b*2560;
    for (int i=t;i<2560;i+=256){
        ((float*)sla)[i] = lstm_a[base+i];
        ((float*)slv)[i] = lstm_v[base+i];
    }
    __syncthreads();

    // ---- branch GEMMs (f32 exact) ----
    {
        float a1[10], a2[10];
        #pragma unroll
        for (int r=0;r<10;r++){ a1[r]=0.f; a2[r]=0.f; }
        #pragma unroll 4
        for (int k=0;k<256;k++){
            float w1 = vL1[k*256+t], w2 = vL2[k*256+t];
            #pragma unroll
            for (int r=0;r<10;r++){ float x=slv[r][k]; a1[r]+=x*w1; a2[r]+=x*w2; }
        }
        #pragma unroll
        for (int r=0;r<10;r++){ sb1v[r][t]=fmaxf(a1[r],0.f); sb2v[r][t]=fmaxf(a2[r],0.f); }
        #pragma unroll
        for (int r=0;r<10;r++){ a1[r]=0.f; a2[r]=0.f; }
        #pragma unroll 4
        for (int k=0;k<256;k++){
            float w1 = aL1[k*256+t], w2 = aL2[k*256+t];
            #pragma unroll
            for (int r=0;r<10;r++){ float x=sla[r][k]; a1[r]+=x*w1; a2[r]+=x*w2; }
        }
        #pragma unroll
        for (int r=0;r<10;r++){ sb1a[r][t]=fmaxf(a1[r],0.f); sb2a[r][t]=fmaxf(a2[r],0.f); }
    }
    __syncthreads();

    // ---- att = relu(v_b2 @ a_b1^T / 16), norm-thr both ways ----
    if (t < 100){
        int v = t/10, a = t - v*10;
        float acc=0.f;
        for (int k=0;k<256;k++) acc += sb2v[v][k]*sb1a[a][k];
        satt[t] = fmaxf(acc*(1.0f/16.0f), 0.f);
    }
    __syncthreads();
    float thr = thrp[0];
    if (t < 10){
        int v = t;
        float rs=0.f; for(int a=0;a<10;a++) rs += satt[v*10+a];
        float inv = 1.f/(rs+1e-8f);
        float tmp[10]; float rs2=0.f;
        for(int a=0;a<10;a++){ float x = satt[v*10+a]*inv; x = (x>thr)?x:0.f; tmp[a]=x; rs2+=x; }
        float inv2 = 1.f/(rs2+1e-8f);
        for(int a=0;a<10;a++) s_v2a[v*10+a] = tmp[a]*inv2;
    } else if (t>=16 && t<26){
        int a = t-16;
        float cs=0.f; for(int v=0;v<10;v++) cs += satt[v*10+a];
        float inv = 1.f/(cs+1e-8f);
        float tmp[10]; float cs2=0.f;
        for(int v=0;v<10;v++){ float x = satt[v*10+a]*inv; x=(x>thr)?x:0.f; tmp[v]=x; cs2+=x; }
        float inv2 = 1.f/(cs2+1e-8f);
        for(int v=0;v<10;v++) s_a2v[a*10+v] = tmp[v]*inv2;
    }
    __syncthreads();

    // ---- psp residuals ----
    #pragma unroll
    for (int v=0;v<10;v++){
        float acc = slv[v][t];
        #pragma unroll
        for (int a=0;a<10;a++) acc += s_v2a[v*10+a]*sb2a[a][t];
        spv[v][t] = acc;
    }
    #pragma unroll
    for (int a=0;a<10;a++){
        float acc = sla[a][t];
        #pragma unroll
        for (int v=0;v<10;v++) acc += s_a2v[a*10+v]*sb1v[v][t];
        spa[a][t] = acc;
    }
    __syncthreads();

    // ---- vfc/afc GEMM (f32) + relu ----
    float fv[10], fa2[10];
    #pragma unroll
    for (int r=0;r<10;r++){ fv[r]=0.f; fa2[r]=0.f; }
    #pragma unroll 4
    for (int k=0;k<256;k++){
        float wv = vfc[k*256+t], wa = afc[k*256+t];
        #pragma unroll
        for (int r=0;r<10;r++){ fv[r]+=spv[r][k]*wv; fa2[r]+=spa[r][k]*wa; }
    }
    #pragma unroll
    for (int r=0;r<10;r++){ fv[r]=fmaxf(fv[r],0.f); fa2[r]=fmaxf(fa2[r],0.f); }

    // ---- LN partial sums per wave ----
    #pragma unroll
    for (int r=0;r<10;r++){
        float s1 = wred64(fv[r]);
        float s2 = wred64(fv[r]*fv[r]);
        float s3 = wred64(fa2[r]);
        float s4 = wred64(fa2[r]*fa2[r]);
        if (lane==0){
            sredp[r*16 + 0*4 + w] = s1; sredp[r*16 + 1*4 + w] = s2;
            sredp[r*16 + 2*4 + w] = s3; sredp[r*16 + 3*4 + w] = s4;
        }
    }
    __syncthreads();
    float gt = ln_g[t], bt2 = ln_b[t];
    #pragma unroll
    for (int r=0;r<10;r++){
        float s1 = sredp[r*16+0]+sredp[r*16+1]+sredp[r*16+2]+sredp[r*16+3];
        float s2 = sredp[r*16+4]+sredp[r*16+5]+sredp[r*16+6]+sredp[r*16+7];
        float s3 = sredp[r*16+8]+sredp[r*16+9]+sredp[r*16+10]+sredp[r*16+11];
        float s4 = sredp[r*16+12]+sredp[r*16+13]+sredp[r*16+14]+sredp[r*16+15];
        float muv = s1*(1.f/256.f);
        float varv = s2*(1.f/256.f) - muv*muv;
        float rsv = 1.f/sqrtf(varv+1e-6f);
        float vln = (fv[r]-muv)*rsv*gt + bt2;
        float mua = s3*(1.f/256.f);
        float vara = s4*(1.f/256.f) - mua*mua;
        float rsa = 1.f/sqrtf(vara+1e-6f);
        float aln = (fa2[r]-mua)*rsa*gt + bt2;
        float fu = 0.5f*(vln+aln);
        dout[(size_t)(b*10+r)*256 + t] = fu;
        sfu[r][t] = fu;
        float c1 = wred64(vln*vln);
        float c2 = wred64(aln*aln);
        float c3 = wred64(vln*aln);
        if (lane==0){
            scos[r*12 + 0*4 + w] = c1; scos[r*12 + 1*4 + w] = c2; scos[r*12 + 2*4 + w] = c3;
        }
    }
    __syncthreads();
    if (t < 10){
        int r = t;
        float nv2 = scos[r*12+0]+scos[r*12+1]+scos[r*12+2]+scos[r*12+3];
        float na2 = scos[r*12+4]+scos[r*12+5]+scos[r*12+6]+scos[r*12+7];
        float dva = scos[r*12+8]+scos[r*12+9]+scos[r*12+10]+scos[r*12+11];
        float nv = fmaxf(sqrtf(nv2), 1e-12f);
        float na = fmaxf(sqrtf(na2), 1e-12f);
        dout[729600 + b*10 + r] = dva/(nv*na);
    }

    // ---- MLP: fuse @ L1w (relu) @ L2w ----
    #pragma unroll
    for (int pass=0; pass<3; ++pass){
        int r = pass*4 + w;
        if (r < 10){
            float acc = 0.f;
            for (int k4=0;k4<64;k4++){
                float4 f4 = *(const float4*)&sfu[r][k4*4];
                acc += f4.x*L1w[(k4*4)*64+lane] + f4.y*L1w[(k4*4+1)*64+lane]
                     + f4.z*L1w[(k4*4+2)*64+lane] + f4.w*L1w[(k4*4+3)*64+lane];
            }
            s64[r][lane] = fmaxf(acc, 0.f);
        }
    }
    __syncthreads();
    for (int i=t; i<290; i+=256){
        int r = i/29, j = i - r*29;
        float acc = 0.f;
        #pragma unroll
        for (int k=0;k<64;k++) acc += s64[r][k]*L2w[k*29+j];
        dout[655360 + (size_t)(b*10+r)*29 + j] = acc;
    }
}

// =======================================================================
extern "C" void kernel_launch(void* const* d_in, const int* in_sizes, int n_in,
                              void* d_out, int out_size, void* d_ws, size_t ws_size,
                              hipStream_t stream) {
    const float* audio  = (const float*)d_in[0];
    const float* video  = (const float*)d_in[1];
    const float* thrp   = (const float*)d_in[2];
    const float* fa_w1  = (const float*)d_in[3];
    const float* fa_w2  = (const float*)d_in[4];
    const float* av_aw  = (const float*)d_in[5];
    const float* av_ab  = (const float*)d_in[6];
    const float* av_vw  = (const float*)d_in[7];
    const float* av_vb  = (const float*)d_in[8];
    const float* av_v2w = (const float*)d_in[9];
    const float* av_gw  = (const float*)d_in[10];
    const float* av_hw  = (const float*)d_in[11];
    const float* fv_w1  = (const float*)d_in[12];
    const float* fv_w2  = (const float*)d_in[13];
    const float* la_wih = (const float*)d_in[14];
    const float* la_whh = (const float*)d_in[15];
    const float* la_b   = (const float*)d_in[16];
    const float* lv_wih = (const float*)d_in[17];
    const float* lv_whh = (const float*)d_in[18];
    const float* lv_b   = (const float*)d_in[19];
    const float* vL1    = (const float*)d_in[20];
    const float* vL2    = (const float*)d_in[21];
    const float* aL1    = (const float*)d_in[22];
    const float* aL2    = (const float*)d_in[23];
    const float* vfc    = (const float*)d_in[24];
    const float* afc    = (const float*)d_in[25];
    const float* ln_g   = (const float*)d_in[26];
    const float* ln_b   = (const float*)d_in[27];
    const float* L1w    = (const float*)d_in[28];
    const float* L2w    = (const float*)d_in[29];
    float* dout = (float*)d_out;
    float* ws = (float*)d_ws;

    // workspace layout (float offsets)
    float* faW  = ws;                 // 16384
    float* fvW  = ws + 16384;         // 65536
    float* gGA  = ws + 409600;        // 125440
    float* vT   = ws + 535040;        // 1310720
    float* xpA  = ws + 2173440;       // 2621440
    float* xpV  = ws + 4794880;       // 2621440
    float* la   = ws + 7416320;       // 655360
    float* lv   = ws + 8071680;       // 655360
    _Float16* Bh = (_Float16*)(ws + 12659200);
    _Float16* Bl = (_Float16*)(ws + 12790272);
    _Float16* Wh = (_Float16*)(ws + 12921344);
    _Float16* Wl = (_Float16*)(ws + 12937728);
    _Float16* PKfv_h = (_Float16*)(ws + 12954112);
    _Float16* PKfv_l = (_Float16*)(ws + 12986880);
    _Float16* PKxv_h = (_Float16*)(ws + 13150720);
    _Float16* PKxv_l = (_Float16*)(ws + 13216256);
    float* vfea = ws + 13675008;      // 327680

    k_prep<<<1472, 256, 0, stream>>>(fa_w1, fa_w2, faW, fv_w1, fv_w2, fvW,
                                     av_vw, Bh, Bl, av_v2w, Wh, Wl);
    k_prep2<<<768, 256, 0, stream>>>(fvW, la_wih, lv_wih,
                                     PKfv_h, PKfv_l, PKxv_h, PKxv_l);
    k_faga2<<<640, 256, 0, stream>>>(audio, faW, av_aw, av_ab, av_gw,
                                     la_wih, la_b, gGA, xpA);
    k_avga_fused<<<2560, 256, 0, stream>>>(video, Bh, Bl, av_vb, Wh, Wl,
                                           gGA, av_hw, vT);
    // vfea = vT @ fvW  [2560,512]x[512,128]
    k_gemm<2,2,false,false><<<dim3(80,1), 256, 0, stream>>>(
        vT, 512, PKfv_h, PKfv_l, nullptr, vfea, 128, 16, 8);
    // xpV = vfea @ [wihV_f|wihV_b] + lv_b
    k_gemm<2,4,true,false><<<dim3(80,4), 256, 0, stream>>>(
        vfea, 128, PKxv_h, PKxv_l, lv_b, xpV, 1024, 4, 64);
    k_lstm<<<256, 256, 0, stream>>>(xpA, xpV, la_whh, lv_whh, la, lv);
    k_tail<<<256, 256, 0, stream>>>(la, lv, vL1, vL2, aL1, aL2, vfc, afc,
                                    thrp, ln_g, ln_b, L1w, L2w, dout);
}